// Round 4
// baseline (1252.947 us; speedup 1.0000x reference)
//
#include <hip/hip_runtime.h>
#include <cstdint>
#include <cstddef>

typedef __attribute__((ext_vector_type(8))) __bf16 bf16x8;
typedef __attribute__((ext_vector_type(4))) float  f32x4;

static_assert(sizeof(bf16x8) == 16, "bf16x8 must be 16B");
static_assert(sizeof(f32x4) == 16, "f32x4 must be 16B");

__device__ __forceinline__ float fast_tanh(float x) {
    // tanh(x) = 1 - 2/(e^{2x}+1); v_exp + v_rcp. Handles +-inf correctly.
    float e = __expf(2.0f * x);
    return 1.0f - 2.0f * __builtin_amdgcn_rcpf(e + 1.0f);
}

// ---- K0a: bias = b_ih + b_hh ; block 0 zeroes the group-barrier counters ----
__global__ void k_bias(const float* __restrict__ b_ih, const float* __restrict__ b_hh,
                       float* __restrict__ bias, int* __restrict__ cnt) {
    int i = blockIdx.x * 256 + threadIdx.x;  // grid 4
    bias[i] = b_ih[i] + b_hh[i];
    if (blockIdx.x == 0) cnt[threadIdx.x] = 0;  // 16 counters, 64B stride
}

// ---- K0b: W_hh fp32 -> bf16 pre-shuffled into MFMA B-fragment order ----
// Ws[(((t*32 + c)*64) + L)*8 + j] = W[t*16 + (L&15)][c*32 + (L>>4)*8 + j]
__global__ void k_shufw(const float* __restrict__ W, __bf16* __restrict__ Ws) {
    int id = blockIdx.x * 256 + threadIdx.x;  // grid 512 -> 131072 = 64t*32c*64L
    int t = id >> 11;
    int c = (id >> 6) & 31;
    int L = id & 63;
    const float* src = W + (size_t)(t * 16 + (L & 15)) * 1024 + c * 32 + (L >> 4) * 8;
    __bf16* dst = Ws + (size_t)id * 8;
#pragma unroll
    for (int j = 0; j < 8; ++j) dst[j] = (__bf16)src[j];
}

// ---- K1a: M = Bw @ Bw^T (64x64). 64 blocks, block i computes row i. ----
__global__ void k_gram(const float* __restrict__ Bw, float* __restrict__ M) {
    int i = blockIdx.x;                 // 64 blocks
    int j = threadIdx.x >> 2;           // 64 cols
    int q = threadIdx.x & 3;            // K-quarter
    const float4* a = (const float4*)(Bw + (size_t)i * 1024) + q * 64;
    const float4* b = (const float4*)(Bw + (size_t)j * 1024) + q * 64;
    float acc = 0.f;
#pragma unroll 8
    for (int t = 0; t < 64; ++t) {
        float4 av = a[t], bv = b[t];
        acc += av.x * bv.x + av.y * bv.y + av.z * bv.z + av.w * bv.w;
    }
    acc += __shfl_xor(acc, 1);
    acc += __shfl_xor(acc, 2);
    if (q == 0) M[i * 64 + j] = acc;
}

// ---- K1b: Minv via Newton-Schulz, conflict-free LDS version ----
__global__ __launch_bounds__(1024) void k_newton(const float* __restrict__ M,
                                                 float* __restrict__ Minv) {
    __shared__ float Mm[4096];
    __shared__ float X[4096];
    __shared__ float Tt[4096];   // T = M@X stored transposed
    const int tid = threadIdx.x;
    const int i = tid & 63;
    const int w = tid >> 6;      // 16 waves, cols w*4 + jj
    for (int p = tid; p < 4096; p += 1024) {
        Mm[p] = M[p];
        int r = p >> 6, c2 = p & 63;
        X[p] = (r == c2) ? 0.941f : 0.0f;   // spectrum of M in [0.5625,1.5625]
    }
    __syncthreads();
    for (int it = 0; it < 6; ++it) {
        float r[4] = {0.f, 0.f, 0.f, 0.f};
        for (int kk = 0; kk < 64; ++kk) {
            float mv = Mm[(kk << 6) + i];                         // M[i][kk] (sym)
            float4 x4 = *(const float4*)&X[(kk << 6) + (w << 2)]; // broadcast
            r[0] += mv * x4.x; r[1] += mv * x4.y; r[2] += mv * x4.z; r[3] += mv * x4.w;
        }
#pragma unroll
        for (int jj = 0; jj < 4; ++jj) Tt[(((w << 2) + jj) << 6) + i] = r[jj];
        __syncthreads();
        float r2[4];
#pragma unroll
        for (int jj = 0; jj < 4; ++jj) r2[jj] = 2.f * X[(((w << 2) + jj) << 6) + i];
        for (int kq = 0; kq < 16; ++kq) {
            float xv0 = X[((kq * 4 + 0) << 6) + i];
            float xv1 = X[((kq * 4 + 1) << 6) + i];
            float xv2 = X[((kq * 4 + 2) << 6) + i];
            float xv3 = X[((kq * 4 + 3) << 6) + i];
#pragma unroll
            for (int jj = 0; jj < 4; ++jj) {
                float4 t4 = *(const float4*)&Tt[(((w << 2) + jj) << 6) + (kq << 2)];
                r2[jj] -= xv0 * t4.x + xv1 * t4.y + xv2 * t4.z + xv3 * t4.w;
            }
        }
        __syncthreads();
#pragma unroll
        for (int jj = 0; jj < 4; ++jj) X[(((w << 2) + jj) << 6) + i] = r2[jj];
        __syncthreads();
    }
    for (int p = tid; p < 4096; p += 1024) Minv[p] = X[p];
}

// ---- K2a: T1 = X_reset @ Minv (Minv symmetric), (1024 x 64) ----
__global__ void k_t1(const float* __restrict__ x, const float* __restrict__ Minv,
                     float* __restrict__ T1) {
    int id = blockIdx.x * 256 + threadIdx.x;  // 256 blocks
    int r = id >> 6, xp = id & 63;
    const float* xr = x + ((size_t)(r >> 4) * 1024 + (size_t)(r & 15) * 64) * 64;
    const float* mr = Minv + (size_t)xp * 64;
    float acc = 0.f;
    for (int t = 0; t < 64; ++t) acc += xr[t] * mr[t];
    T1[id] = acc;
}

// ---- K2b: H0 = T1 @ Bw  (1024 x 1024), row-major bf16 ----
__global__ void k_h0(const float* __restrict__ T1, const float* __restrict__ Bw,
                     __bf16* __restrict__ H0) {
    int r = blockIdx.y;
    int z = blockIdx.x * 256 + threadIdx.x;  // grid (4,1024)
    const float* t1 = T1 + (size_t)r * 64;
    float acc = 0.f;
    for (int xp = 0; xp < 64; ++xp) acc += t1[xp] * Bw[(size_t)xp * 1024 + z];
    H0[(size_t)r * 1024 + z] = (__bf16)acc;
}

// ---- K3 (host-side fallback only): one recurrence step ----
__global__ __launch_bounds__(256) void k_step(
    const __bf16* __restrict__ Hin, const __bf16* __restrict__ Ws,
    const float* __restrict__ bias, __bf16* __restrict__ Hout,
    float* __restrict__ out, int kstep) {
    const int tid = threadIdx.x;
    const int w = tid >> 6;
    const int lane = tid & 63;
    const int row = lane & 15;
    const int quad = lane >> 4;
    const int bm = blockIdx.x, bn = blockIdx.y;

    const __bf16* Arow = Hin + (size_t)(bm * 64 + w * 16 + row) * 1024 + quad * 8;
    const __bf16* B0 = Ws + ((size_t)((bn * 2 + 0) * 32) * 64 + lane) * 8;
    const __bf16* B1 = Ws + ((size_t)((bn * 2 + 1) * 32) * 64 + lane) * 8;

    f32x4 acc0 = {0.f, 0.f, 0.f, 0.f};
    f32x4 acc1 = {0.f, 0.f, 0.f, 0.f};
#pragma unroll 8
    for (int c = 0; c < 32; ++c) {
        bf16x8 a = *(const bf16x8*)(Arow + c * 32);
        bf16x8 b0 = *(const bf16x8*)(B0 + (size_t)c * 512);
        bf16x8 b1 = *(const bf16x8*)(B1 + (size_t)c * 512);
        acc0 = __builtin_amdgcn_mfma_f32_16x16x32_bf16(a, b0, acc0, 0, 0, 0);
        acc1 = __builtin_amdgcn_mfma_f32_16x16x32_bf16(a, b1, acc1, 0, 0, 0);
    }
#pragma unroll
    for (int nt = 0; nt < 2; ++nt) {
        const f32x4 acc = nt ? acc1 : acc0;
        const int col = bn * 32 + nt * 16 + row;
        const float bv = bias[col];
#pragma unroll
        for (int i = 0; i < 4; ++i) {
            const int m = bm * 64 + w * 16 + quad * 4 + i;
            float v = tanhf(acc[i] + bv);
            const int b_ = m >> 4, s_ = m & 15;
            out[((size_t)b_ * 1024 + (size_t)s_ * 64 + kstep) * 1024 + col] = v;
            Hout[(size_t)m * 1024 + col] = (__bf16)v;
        }
    }
}

// ---- K3': persistent cooperative recurrence kernel (round-1 semantics, re-scheduled) --
// Grid 256 x 256thr, 1 block/CU. Block (bm=bid&15, bn=bid>>4) owns tile rows
// bm*64..+64, cols bn*64..+64 for all 64 steps; B-slice resident in LDS.
// Per-step all-gather within the 16-block bm-group via agent-scope (LLC) H
// exchange + monotonic counter barrier (proven in round 1). Changes vs round 1:
//  - A: all 64 u64 agent loads issued up front (compiler-tracked vmcnt) -> 1 LLC RT
//  - epilogue transposed through LDS: H = 4x coalesced u64 agent stores/thread,
//    out = 4x dwordx4 nontemporal stores/thread
//  - out stores issued AFTER the barrier poll: HBM drain overlaps next step
__global__ __launch_bounds__(256, 1) void k_persist(
    const __bf16* __restrict__ Ws, const float* __restrict__ bias,
    __bf16* __restrict__ H0, __bf16* __restrict__ H1,
    float* __restrict__ out, int* cnt) {
    __shared__ __bf16 Bs[65536];     // 128 KB: 4 tiles x 32 c x 64 lanes x 8
    __shared__ float oT[64 * 68];    // 17 KB transpose buffer (stride 68 vs banks)
    const int tid = threadIdx.x;
    const int lane = tid & 63;
    const int w = tid >> 6;
    const int row = lane & 15, quad = lane >> 4;
    const int bm = blockIdx.x & 15;
    const int bn = blockIdx.x >> 4;

    {   // stage this block's 128 KB B-slice (tiles 4bn..4bn+3), contiguous copy
        const bf16x8* src = (const bf16x8*)(Ws + ((size_t)bn << 16));
        bf16x8* dst = (bf16x8*)Bs;
#pragma unroll
        for (int it = 0; it < 32; ++it) dst[it * 256 + tid] = src[it * 256 + tid];
    }
    float bv[4];
#pragma unroll
    for (int nt = 0; nt < 4; ++nt) bv[nt] = bias[bn * 64 + nt * 16 + row];
    __syncthreads();

    const size_t aoff = (size_t)(bm * 64 + w * 16 + row) * 1024 + quad * 8;
    int* gcnt = cnt + bm * 16;   // 64B-padded group counters
    const bf16x8* Bl = (const bf16x8*)Bs + lane;

    // transposed-epilogue thread mapping: thread -> (local row tr, 16-col chunk tc)
    const int tr = tid >> 2;
    const int tc = (tid & 3) << 4;
    const int gm = bm * 64 + tr;                    // global H row
    float* outp = out + ((size_t)(gm >> 4) * 1024 + (size_t)(gm & 15) * 64) * 1024
                      + (size_t)bn * 64 + tc;       // + k*1024 per step
    const size_t hoff = (size_t)gm * 1024 + (size_t)(bn * 64 + tc);

    for (int k = 0; k < 64; ++k) {
        const __bf16* Hin = (k & 1) ? H1 : H0;
        __bf16* Hout = (k & 1) ? H0 : H1;
        const unsigned long long* Aq = (const unsigned long long*)(Hin + aoff);

        // ---- A phase: 64 agent-scope u64 loads, all in flight at once ----
        bf16x8 av[32];
#pragma unroll
        for (int c = 0; c < 32; ++c) {
            union { bf16x8 v; unsigned long long q[2]; } u;
            u.q[0] = __hip_atomic_load(Aq + c * 8,     __ATOMIC_RELAXED,
                                       __HIP_MEMORY_SCOPE_AGENT);
            u.q[1] = __hip_atomic_load(Aq + c * 8 + 1, __ATOMIC_RELAXED,
                                       __HIP_MEMORY_SCOPE_AGENT);
            av[c] = u.v;
        }

        f32x4 acc0 = {0.f, 0.f, 0.f, 0.f};
        f32x4 acc1 = acc0, acc2 = acc0, acc3 = acc0;
#pragma unroll
        for (int c = 0; c < 32; ++c) {
            acc0 = __builtin_amdgcn_mfma_f32_16x16x32_bf16(av[c], Bl[(0 * 32 + c) * 64], acc0, 0, 0, 0);
            acc1 = __builtin_amdgcn_mfma_f32_16x16x32_bf16(av[c], Bl[(1 * 32 + c) * 64], acc1, 0, 0, 0);
            acc2 = __builtin_amdgcn_mfma_f32_16x16x32_bf16(av[c], Bl[(2 * 32 + c) * 64], acc2, 0, 0, 0);
            acc3 = __builtin_amdgcn_mfma_f32_16x16x32_bf16(av[c], Bl[(3 * 32 + c) * 64], acc3, 0, 0, 0);
        }

        // ---- epilogue: tanh, stage f32 tile transposed in LDS ----
#pragma unroll
        for (int nt = 0; nt < 4; ++nt) {
            const f32x4 acc = nt == 0 ? acc0 : nt == 1 ? acc1 : nt == 2 ? acc2 : acc3;
#pragma unroll
            for (int i2 = 0; i2 < 4; ++i2) {
                const int r = w * 16 + quad * 4 + i2;
                oT[r * 68 + nt * 16 + row] = fast_tanh(acc[i2] + bv[nt]);
            }
        }
        __syncthreads();   // #1: oT ready (also drains prior step's out stores)

        const f32x4 o0 = *(const f32x4*)&oT[tr * 68 + tc + 0];
        const f32x4 o1 = *(const f32x4*)&oT[tr * 68 + tc + 4];
        const f32x4 o2 = *(const f32x4*)&oT[tr * 68 + tc + 8];
        const f32x4 o3 = *(const f32x4*)&oT[tr * 68 + tc + 12];

        if (k < 63) {
            // H: 16 f32 -> 16 bf16 -> 4 coalesced u64 agent stores
            union { __bf16 h[16]; unsigned long long q[4]; } hp;
#pragma unroll
            for (int j = 0; j < 4; ++j) {
                hp.h[0 + j] = (__bf16)o0[j];
                hp.h[4 + j] = (__bf16)o1[j];
                hp.h[8 + j] = (__bf16)o2[j];
                hp.h[12 + j] = (__bf16)o3[j];
            }
            unsigned long long* hq = (unsigned long long*)(Hout + hoff);
#pragma unroll
            for (int j = 0; j < 4; ++j)
                __hip_atomic_store(hq + j, hp.q[j], __ATOMIC_RELAXED,
                                   __HIP_MEMORY_SCOPE_AGENT);
        }
        __syncthreads();   // #2: per-wave vmcnt(0) drain -> H acked at LLC
        if (k < 63) {
            if (tid == 0) {
                __hip_atomic_fetch_add(gcnt, 1, __ATOMIC_RELAXED,
                                       __HIP_MEMORY_SCOPE_AGENT);
                const int target = (k + 1) * 16;   // monotonic: no reset race
                while (__hip_atomic_load(gcnt, __ATOMIC_RELAXED,
                                         __HIP_MEMORY_SCOPE_AGENT) < target)
                    __builtin_amdgcn_s_sleep(1);
            }
            __syncthreads();   // #3: release block
        }
        // out stores AFTER the barrier: their HBM drain overlaps step k+1
        float* op = outp + (size_t)k * 1024;
        __builtin_nontemporal_store(o0, (f32x4*)(op + 0));
        __builtin_nontemporal_store(o1, (f32x4*)(op + 4));
        __builtin_nontemporal_store(o2, (f32x4*)(op + 8));
        __builtin_nontemporal_store(o3, (f32x4*)(op + 12));
    }
}

extern "C" void kernel_launch(void* const* d_in, const int* in_sizes, int n_in,
                              void* d_out, int out_size, void* d_ws, size_t ws_size,
                              hipStream_t stream) {
    const float* x = (const float*)d_in[0];     // (64,1024,64)
    const float* Bw = (const float*)d_in[1];    // (64,1024)
    const float* W_hh = (const float*)d_in[2];  // (1024,1024)
    const float* b_ih = (const float*)d_in[3];  // (1024,)
    const float* b_hh = (const float*)d_in[4];  // (1024,)
    float* out = (float*)d_out;                 // (64,1024,1024)
    uint8_t* ws = (uint8_t*)d_ws;

    __bf16* Ws = (__bf16*)(ws);                         // 2 MB (shuffled W)
    __bf16* H0 = (__bf16*)(ws + (2ull << 20));          // 2 MB
    __bf16* H1 = (__bf16*)(ws + (4ull << 20));          // 2 MB
    float* bias = (float*)(ws + (6ull << 20));          // 4 KB
    float* Mg = (float*)(ws + (6ull << 20) + 4096);     // 16 KB
    float* Minv = (float*)(ws + (6ull << 20) + 20480);  // 16 KB
    float* T1 = (float*)(ws + (6ull << 20) + 36864);    // 256 KB
    int* cnt = (int*)(ws + (6ull << 20) + 36864 + 262144);  // 1 KB barrier counters

    hipLaunchKernelGGL(k_bias, dim3(4), dim3(256), 0, stream, b_ih, b_hh, bias, cnt);
    hipLaunchKernelGGL(k_shufw, dim3(512), dim3(256), 0, stream, W_hh, Ws);
    hipLaunchKernelGGL(k_gram, dim3(64), dim3(256), 0, stream, Bw, Mg);
    hipLaunchKernelGGL(k_newton, dim3(1), dim3(1024), 0, stream, Mg, Minv);
    hipLaunchKernelGGL(k_t1, dim3(256), dim3(256), 0, stream, x, Minv, T1);
    hipLaunchKernelGGL(k_h0, dim3(4, 1024), dim3(256), 0, stream, T1, Bw, H0);

    const __bf16* Wsp = Ws;
    const float* biasp = bias;
    __bf16* h0p = H0;
    __bf16* h1p = H1;
    float* outp = out;
    int* cntp = cnt;
    void* kargs[] = {&Wsp, &biasp, &h0p, &h1p, &outp, &cntp};
    hipError_t err = hipLaunchCooperativeKernel((void*)k_persist, dim3(256), dim3(256),
                                                kargs, 0, stream);
    if (err != hipSuccess) {
        // fallback: 64-launch path
        __bf16* bufs[2] = {H0, H1};
        for (int k = 0; k < 64; ++k) {
            hipLaunchKernelGGL(k_step, dim3(16, 32), dim3(256), 0, stream,
                               bufs[k & 1], Ws, bias, bufs[(k + 1) & 1], out, k);
        }
    }
}

// Round 5
// 972.695 us; speedup vs baseline: 1.2881x; 1.2881x over previous
//
#include <hip/hip_runtime.h>
#include <cstdint>
#include <cstddef>

typedef __attribute__((ext_vector_type(8))) __bf16 bf16x8;
typedef __attribute__((ext_vector_type(4))) float  f32x4;

static_assert(sizeof(bf16x8) == 16, "bf16x8 must be 16B");
static_assert(sizeof(f32x4) == 16, "f32x4 must be 16B");

__device__ __forceinline__ float fast_tanh(float x) {
    // tanh(x) = 1 - 2/(e^{2x}+1); v_exp + v_rcp. Handles +-inf correctly.
    float e = __expf(2.0f * x);
    return 1.0f - 2.0f * __builtin_amdgcn_rcpf(e + 1.0f);
}

// agent-scope (cross-XCD coherent) 16B load as 2x u64 atomics
__device__ __forceinline__ bf16x8 load_h(const __bf16* p) {
    union { bf16x8 v; unsigned long long q[2]; } u;
    const unsigned long long* qp = (const unsigned long long*)p;
    u.q[0] = __hip_atomic_load(qp, __ATOMIC_RELAXED, __HIP_MEMORY_SCOPE_AGENT);
    u.q[1] = __hip_atomic_load(qp + 1, __ATOMIC_RELAXED, __HIP_MEMORY_SCOPE_AGENT);
    return u.v;
}

// ---- K0a: bias = b_ih + b_hh ; block 0 zeroes the group-barrier counters ----
__global__ void k_bias(const float* __restrict__ b_ih, const float* __restrict__ b_hh,
                       float* __restrict__ bias, int* __restrict__ cnt) {
    int i = blockIdx.x * 256 + threadIdx.x;  // grid 4
    bias[i] = b_ih[i] + b_hh[i];
    if (blockIdx.x == 0) cnt[threadIdx.x] = 0;  // 16 counters, 64B stride
}

// ---- K0b: W_hh fp32 -> bf16 pre-shuffled into MFMA B-fragment order ----
// Ws[(((t*32 + c)*64) + L)*8 + j] = W[t*16 + (L&15)][c*32 + (L>>4)*8 + j]
__global__ void k_shufw(const float* __restrict__ W, __bf16* __restrict__ Ws) {
    int id = blockIdx.x * 256 + threadIdx.x;  // grid 512 -> 131072 = 64t*32c*64L
    int t = id >> 11;
    int c = (id >> 6) & 31;
    int L = id & 63;
    const float* src = W + (size_t)(t * 16 + (L & 15)) * 1024 + c * 32 + (L >> 4) * 8;
    __bf16* dst = Ws + (size_t)id * 8;
#pragma unroll
    for (int j = 0; j < 8; ++j) dst[j] = (__bf16)src[j];
}

// ---- K1a: M = Bw @ Bw^T (64x64). 64 blocks, block i computes row i. ----
__global__ void k_gram(const float* __restrict__ Bw, float* __restrict__ M) {
    int i = blockIdx.x;                 // 64 blocks
    int j = threadIdx.x >> 2;           // 64 cols
    int q = threadIdx.x & 3;            // K-quarter
    const float4* a = (const float4*)(Bw + (size_t)i * 1024) + q * 64;
    const float4* b = (const float4*)(Bw + (size_t)j * 1024) + q * 64;
    float acc = 0.f;
#pragma unroll 8
    for (int t = 0; t < 64; ++t) {
        float4 av = a[t], bv = b[t];
        acc += av.x * bv.x + av.y * bv.y + av.z * bv.z + av.w * bv.w;
    }
    acc += __shfl_xor(acc, 1);
    acc += __shfl_xor(acc, 2);
    if (q == 0) M[i * 64 + j] = acc;
}

// ---- K1b: Minv via Newton-Schulz, conflict-free LDS version ----
__global__ __launch_bounds__(1024) void k_newton(const float* __restrict__ M,
                                                 float* __restrict__ Minv) {
    __shared__ float Mm[4096];
    __shared__ float X[4096];
    __shared__ float Tt[4096];   // T = M@X stored transposed
    const int tid = threadIdx.x;
    const int i = tid & 63;
    const int w = tid >> 6;      // 16 waves, cols w*4 + jj
    for (int p = tid; p < 4096; p += 1024) {
        Mm[p] = M[p];
        int r = p >> 6, c2 = p & 63;
        X[p] = (r == c2) ? 0.941f : 0.0f;   // spectrum of M in [0.5625,1.5625]
    }
    __syncthreads();
    for (int it = 0; it < 6; ++it) {
        float r[4] = {0.f, 0.f, 0.f, 0.f};
        for (int kk = 0; kk < 64; ++kk) {
            float mv = Mm[(kk << 6) + i];                         // M[i][kk] (sym)
            float4 x4 = *(const float4*)&X[(kk << 6) + (w << 2)]; // broadcast
            r[0] += mv * x4.x; r[1] += mv * x4.y; r[2] += mv * x4.z; r[3] += mv * x4.w;
        }
#pragma unroll
        for (int jj = 0; jj < 4; ++jj) Tt[(((w << 2) + jj) << 6) + i] = r[jj];
        __syncthreads();
        float r2[4];
#pragma unroll
        for (int jj = 0; jj < 4; ++jj) r2[jj] = 2.f * X[(((w << 2) + jj) << 6) + i];
        for (int kq = 0; kq < 16; ++kq) {
            float xv0 = X[((kq * 4 + 0) << 6) + i];
            float xv1 = X[((kq * 4 + 1) << 6) + i];
            float xv2 = X[((kq * 4 + 2) << 6) + i];
            float xv3 = X[((kq * 4 + 3) << 6) + i];
#pragma unroll
            for (int jj = 0; jj < 4; ++jj) {
                float4 t4 = *(const float4*)&Tt[(((w << 2) + jj) << 6) + (kq << 2)];
                r2[jj] -= xv0 * t4.x + xv1 * t4.y + xv2 * t4.z + xv3 * t4.w;
            }
        }
        __syncthreads();
#pragma unroll
        for (int jj = 0; jj < 4; ++jj) X[(((w << 2) + jj) << 6) + i] = r2[jj];
        __syncthreads();
    }
    for (int p = tid; p < 4096; p += 1024) Minv[p] = X[p];
}

// ---- K2a: T1 = X_reset @ Minv (Minv symmetric), (1024 x 64) ----
__global__ void k_t1(const float* __restrict__ x, const float* __restrict__ Minv,
                     float* __restrict__ T1) {
    int id = blockIdx.x * 256 + threadIdx.x;  // 256 blocks
    int r = id >> 6, xp = id & 63;
    const float* xr = x + ((size_t)(r >> 4) * 1024 + (size_t)(r & 15) * 64) * 64;
    const float* mr = Minv + (size_t)xp * 64;
    float acc = 0.f;
    for (int t = 0; t < 64; ++t) acc += xr[t] * mr[t];
    T1[id] = acc;
}

// ---- K2b: H0 = T1 @ Bw  (1024 x 1024), row-major bf16 ----
__global__ void k_h0(const float* __restrict__ T1, const float* __restrict__ Bw,
                     __bf16* __restrict__ H0) {
    int r = blockIdx.y;
    int z = blockIdx.x * 256 + threadIdx.x;  // grid (4,1024)
    const float* t1 = T1 + (size_t)r * 64;
    float acc = 0.f;
    for (int xp = 0; xp < 64; ++xp) acc += t1[xp] * Bw[(size_t)xp * 1024 + z];
    H0[(size_t)r * 1024 + z] = (__bf16)acc;
}

// ---- K3 (host-side fallback only): one recurrence step ----
__global__ __launch_bounds__(256) void k_step(
    const __bf16* __restrict__ Hin, const __bf16* __restrict__ Ws,
    const float* __restrict__ bias, __bf16* __restrict__ Hout,
    float* __restrict__ out, int kstep) {
    const int tid = threadIdx.x;
    const int w = tid >> 6;
    const int lane = tid & 63;
    const int row = lane & 15;
    const int quad = lane >> 4;
    const int bm = blockIdx.x, bn = blockIdx.y;

    const __bf16* Arow = Hin + (size_t)(bm * 64 + w * 16 + row) * 1024 + quad * 8;
    const __bf16* B0 = Ws + ((size_t)((bn * 2 + 0) * 32) * 64 + lane) * 8;
    const __bf16* B1 = Ws + ((size_t)((bn * 2 + 1) * 32) * 64 + lane) * 8;

    f32x4 acc0 = {0.f, 0.f, 0.f, 0.f};
    f32x4 acc1 = {0.f, 0.f, 0.f, 0.f};
#pragma unroll 8
    for (int c = 0; c < 32; ++c) {
        bf16x8 a = *(const bf16x8*)(Arow + c * 32);
        bf16x8 b0 = *(const bf16x8*)(B0 + (size_t)c * 512);
        bf16x8 b1 = *(const bf16x8*)(B1 + (size_t)c * 512);
        acc0 = __builtin_amdgcn_mfma_f32_16x16x32_bf16(a, b0, acc0, 0, 0, 0);
        acc1 = __builtin_amdgcn_mfma_f32_16x16x32_bf16(a, b1, acc1, 0, 0, 0);
    }
#pragma unroll
    for (int nt = 0; nt < 2; ++nt) {
        const f32x4 acc = nt ? acc1 : acc0;
        const int col = bn * 32 + nt * 16 + row;
        const float bv = bias[col];
#pragma unroll
        for (int i = 0; i < 4; ++i) {
            const int m = bm * 64 + w * 16 + quad * 4 + i;
            float v = tanhf(acc[i] + bv);
            const int b_ = m >> 4, s_ = m & 15;
            out[((size_t)b_ * 1024 + (size_t)s_ * 64 + kstep) * 1024 + col] = v;
            Hout[(size_t)m * 1024 + col] = (__bf16)v;
        }
    }
}

// ---- K3': persistent cooperative recurrence kernel ----
// Grid 256 x 256thr, 1 block/CU (LDS 128 KB). Block (bm=bid&15, bn=bid>>4) owns
// tile rows bm*64..+64, cols bn*64..+64 for all 64 steps; B-slice in LDS.
// OPERAND-SWAPPED MFMA: acc = mfma(b_frag, a_frag) computes D^T, so each lane
// holds output row (lane&15) x 4 consecutive cols (quad*4+reg) -> coalesced
// 16B out stores and 8B H stores straight from registers, no LDS transpose.
// A-phase: depth-16 rotating register pipeline of agent-scope u64 loads
// (statically indexed, ~64 VGPRs -> no spill, compiler-tracked vmcnt).
__global__ __launch_bounds__(256, 1) void k_persist(
    const __bf16* __restrict__ Ws, const float* __restrict__ bias,
    __bf16* __restrict__ H0, __bf16* __restrict__ H1,
    float* __restrict__ out, int* cnt) {
    __shared__ __bf16 Bs[65536];   // 128 KB: 4 tiles x 32 c x 64 lanes x 8
    const int tid = threadIdx.x;
    const int lane = tid & 63;
    const int w = tid >> 6;
    const int row = lane & 15, quad = lane >> 4;
    const int bm = blockIdx.x & 15;
    const int bn = blockIdx.x >> 4;

    {   // stage this block's 128 KB B-slice (tiles 4bn..4bn+3), contiguous copy
        const bf16x8* src = (const bf16x8*)(Ws + ((size_t)bn << 16));
        bf16x8* dst = (bf16x8*)Bs;
#pragma unroll
        for (int it = 0; it < 32; ++it) dst[it * 256 + tid] = src[it * 256 + tid];
    }
    // bias per lane: 4 consecutive cols per n-tile (operand-swapped layout)
    f32x4 bv4[4];
#pragma unroll
    for (int nt = 0; nt < 4; ++nt)
        bv4[nt] = *(const f32x4*)(bias + bn * 64 + nt * 16 + quad * 4);
    __syncthreads();

    const int gm = bm * 64 + w * 16 + row;           // this lane's output H row
    const size_t aoff = (size_t)gm * 1024 + quad * 8;
    const size_t hoff = (size_t)gm * 1024 + bn * 64 + quad * 4;   // bf16 elems
    float* outp = out + ((size_t)(gm >> 4) * 1024 + (size_t)(gm & 15) * 64) * 1024
                      + (size_t)bn * 64 + quad * 4;  // + k*1024 per step
    int* gcnt = cnt + bm * 16;                       // 64B-padded group counters
    const bf16x8* Bl = (const bf16x8*)Bs + lane;

#define KST(AA, CC) \
  acc0 = __builtin_amdgcn_mfma_f32_16x16x32_bf16(Bl[(0 * 32 + (CC)) * 64], AA, acc0, 0, 0, 0); \
  acc1 = __builtin_amdgcn_mfma_f32_16x16x32_bf16(Bl[(1 * 32 + (CC)) * 64], AA, acc1, 0, 0, 0); \
  acc2 = __builtin_amdgcn_mfma_f32_16x16x32_bf16(Bl[(2 * 32 + (CC)) * 64], AA, acc2, 0, 0, 0); \
  acc3 = __builtin_amdgcn_mfma_f32_16x16x32_bf16(Bl[(3 * 32 + (CC)) * 64], AA, acc3, 0, 0, 0);

    for (int k = 0; k < 64; ++k) {
        const __bf16* Hin = (k & 1) ? H1 : H0;
        __bf16* Hout = (k & 1) ? H0 : H1;
        const __bf16* A = Hin + aoff;

        f32x4 acc0 = {0.f, 0.f, 0.f, 0.f};
        f32x4 acc1 = acc0, acc2 = acc0, acc3 = acc0;

        // depth-16 rotating pipeline: 16 chunks in flight, static indices
        bf16x8 av[16];
#pragma unroll
        for (int c = 0; c < 16; ++c) av[c] = load_h(A + c * 32);
#pragma unroll
        for (int c = 0; c < 16; ++c) {
            KST(av[c], c)
            av[c] = load_h(A + (c + 16) * 32);
        }
#pragma unroll
        for (int c = 0; c < 16; ++c) {
            KST(av[c], c + 16)
        }

        // epilogue: bias + tanh in registers (lane owns row gm, cols quad*4+..)
        f32x4 o[4];
#pragma unroll
        for (int nt = 0; nt < 4; ++nt) {
            const f32x4 acc = nt == 0 ? acc0 : nt == 1 ? acc1 : nt == 2 ? acc2 : acc3;
#pragma unroll
            for (int j = 0; j < 4; ++j) o[nt][j] = fast_tanh(acc[j] + bv4[nt][j]);
        }

        if (k < 63) {
            // H: 4 cols bf16 = 8B per n-tile, coalesced (16 lanes fill 128B/row)
#pragma unroll
            for (int nt = 0; nt < 4; ++nt) {
                union { __bf16 h[4]; unsigned long long q; } hp;
#pragma unroll
                for (int j = 0; j < 4; ++j) hp.h[j] = (__bf16)o[nt][j];
                __hip_atomic_store((unsigned long long*)(Hout + hoff + nt * 16),
                                   hp.q, __ATOMIC_RELAXED, __HIP_MEMORY_SCOPE_AGENT);
            }
        }
        __syncthreads();   // drains each wave's H stores (vmcnt 0) + aligns waves
        if (k < 63) {
            if (tid == 0)
                __hip_atomic_fetch_add(gcnt, 1, __ATOMIC_RELAXED,
                                       __HIP_MEMORY_SCOPE_AGENT);
            // out stores AFTER arrive: HBM drain overlaps barrier wait + next step
            float* op = outp + (size_t)k * 1024;
#pragma unroll
            for (int nt = 0; nt < 4; ++nt) *(f32x4*)(op + nt * 16) = o[nt];
            if (tid == 0) {
                const int target = (k + 1) * 16;   // monotonic: no reset race
                while (__hip_atomic_load(gcnt, __ATOMIC_RELAXED,
                                         __HIP_MEMORY_SCOPE_AGENT) < target)
                    __builtin_amdgcn_s_sleep(1);
            }
            __syncthreads();   // release block
        } else {
            float* op = outp + (size_t)k * 1024;
#pragma unroll
            for (int nt = 0; nt < 4; ++nt) *(f32x4*)(op + nt * 16) = o[nt];
        }
    }
#undef KST
}

extern "C" void kernel_launch(void* const* d_in, const int* in_sizes, int n_in,
                              void* d_out, int out_size, void* d_ws, size_t ws_size,
                              hipStream_t stream) {
    const float* x = (const float*)d_in[0];     // (64,1024,64)
    const float* Bw = (const float*)d_in[1];    // (64,1024)
    const float* W_hh = (const float*)d_in[2];  // (1024,1024)
    const float* b_ih = (const float*)d_in[3];  // (1024,)
    const float* b_hh = (const float*)d_in[4];  // (1024,)
    float* out = (float*)d_out;                 // (64,1024,1024)
    uint8_t* ws = (uint8_t*)d_ws;

    __bf16* Ws = (__bf16*)(ws);                         // 2 MB (shuffled W)
    __bf16* H0 = (__bf16*)(ws + (2ull << 20));          // 2 MB
    __bf16* H1 = (__bf16*)(ws + (4ull << 20));          // 2 MB
    float* bias = (float*)(ws + (6ull << 20));          // 4 KB
    float* Mg = (float*)(ws + (6ull << 20) + 4096);     // 16 KB
    float* Minv = (float*)(ws + (6ull << 20) + 20480);  // 16 KB
    float* T1 = (float*)(ws + (6ull << 20) + 36864);    // 256 KB
    int* cnt = (int*)(ws + (6ull << 20) + 36864 + 262144);  // 1 KB barrier counters

    hipLaunchKernelGGL(k_bias, dim3(4), dim3(256), 0, stream, b_ih, b_hh, bias, cnt);
    hipLaunchKernelGGL(k_shufw, dim3(512), dim3(256), 0, stream, W_hh, Ws);
    hipLaunchKernelGGL(k_gram, dim3(64), dim3(256), 0, stream, Bw, Mg);
    hipLaunchKernelGGL(k_newton, dim3(1), dim3(1024), 0, stream, Mg, Minv);
    hipLaunchKernelGGL(k_t1, dim3(256), dim3(256), 0, stream, x, Minv, T1);
    hipLaunchKernelGGL(k_h0, dim3(4, 1024), dim3(256), 0, stream, T1, Bw, H0);

    const __bf16* Wsp = Ws;
    const float* biasp = bias;
    __bf16* h0p = H0;
    __bf16* h1p = H1;
    float* outp = out;
    int* cntp = cnt;
    void* kargs[] = {&Wsp, &biasp, &h0p, &h1p, &outp, &cntp};
    hipError_t err = hipLaunchCooperativeKernel((void*)k_persist, dim3(256), dim3(256),
                                                kargs, 0, stream);
    if (err != hipSuccess) {
        // fallback: 64-launch path
        __bf16* bufs[2] = {H0, H1};
        for (int k = 0; k < 64; ++k) {
            hipLaunchKernelGGL(k_step, dim3(16, 32), dim3(256), 0, stream,
                               bufs[k & 1], Ws, bias, bufs[(k + 1) & 1], out, k);
        }
    }
}